// Round 10
// baseline (575.285 us; speedup 1.0000x reference)
//
#include <hip/hip_runtime.h>
#include <cmath>

#define H 128
#define EPS 1e-5f

typedef __attribute__((ext_vector_type(8))) __bf16 bf16x8;
typedef __attribute__((ext_vector_type(4))) float f32x4;
typedef __attribute__((ext_vector_type(2))) float f32x2;
typedef __attribute__((ext_vector_type(4))) unsigned short u16x4;
typedef __attribute__((ext_vector_type(8))) unsigned short u16x8;
typedef __attribute__((ext_vector_type(4))) int i32x4;

// Fast GELU (sigmoid form), ~7 VALU ops; max abs err ~1e-3 (below bf16
// rounding of the result). Verified R9: absmax unchanged vs erff.
__device__ __forceinline__ float gelu_fast(float x) {
    float t2 = -1.5957691216057308f * fmaf(0.044715f * x * x, x, x); // -2t
    return x * __builtin_amdgcn_rcpf(1.0f + __expf(t2));
}

__device__ __forceinline__ unsigned short f2bfu(float f) {
    __bf16 h = (__bf16)f;   // RNE fptrunc
    return __builtin_bit_cast(unsigned short, h);
}

// ---------------------------------------------------------------------------
// Zero scratch (stats + cnt + cnt2) — in-graph hipMemsetAsync measured 195us
// for 324 KB in R7; this kernel is ~3us.
// ---------------------------------------------------------------------------
__global__ __launch_bounds__(256) void zero_kernel(int* __restrict__ p, int n4)
{
    int i = blockIdx.x * blockDim.x + threadIdx.x;
    const int stride = gridDim.x * blockDim.x;
    i32x4 z = {0, 0, 0, 0};
    for (; i < n4; i += stride)
        reinterpret_cast<i32x4*>(p)[i] = z;
}

// ---------------------------------------------------------------------------
// Counting sort of edges by dst -> perm (dst-grouped edge ids), offs.
// ---------------------------------------------------------------------------
__global__ __launch_bounds__(256) void hist_kernel(const int* __restrict__ dst,
                                                   int* __restrict__ cnt, int E)
{
    int i = blockIdx.x * blockDim.x + threadIdx.x;
    const int stride = gridDim.x * blockDim.x;
    for (; i < E; i += stride) atomicAdd(&cnt[dst[i]], 1);
}

__global__ __launch_bounds__(1024) void scan_kernel(const int* __restrict__ cnt,
                                                    int* __restrict__ offs,
                                                    int Nn, int E)
{
    __shared__ int part[1024];
    const int t = threadIdx.x;
    const int CH = (Nn + 1023) / 1024;
    const int base = t * CH;
    int s = 0;
    for (int i = 0; i < CH; ++i) {
        int idx = base + i;
        if (idx < Nn) s += cnt[idx];
    }
    part[t] = s;
    __syncthreads();
    for (int d = 1; d < 1024; d <<= 1) {
        int v = (t >= d) ? part[t - d] : 0;
        __syncthreads();
        part[t] += v;
        __syncthreads();
    }
    int run = (t > 0) ? part[t - 1] : 0;
    for (int i = 0; i < CH; ++i) {
        int idx = base + i;
        if (idx < Nn) {
            offs[idx] = run;
            run += cnt[idx];
        }
    }
    if (t == 0) offs[Nn] = E;
}

__global__ __launch_bounds__(256) void scatter_perm(const int* __restrict__ dst,
                                                    const int* __restrict__ offs,
                                                    int* __restrict__ cur2,
                                                    int* __restrict__ perm, int E)
{
    int i = blockIdx.x * blockDim.x + threadIdx.x;
    const int stride = gridDim.x * blockDim.x;
    for (; i < E; i += stride) {
        int n = dst[i];
        int p = offs[n] + atomicAdd(&cur2[n], 1);
        perm[p] = i;
    }
}

// ---------------------------------------------------------------------------
// Fused edge phase, WAVE-PRIVATE tiles (no per-tile barrier).
// Each wave grid-strides over 16-edge tiles: stages bf16(posE) into its own
// 4KB LDS slice (coalesced global loads, XOR swizzle; ds ordering within a
// wave needs no __syncthreads), then 32 MFMAs over all 128 output cols with
// W1 fragments ds_read from a block-shared 32KB LDS copy (loaded once, one
// barrier per kernel). Bias folds into the MFMA accumulator init.
// ---------------------------------------------------------------------------
__global__ __launch_bounds__(256, 3) void fused_edge(
    const float* __restrict__ x, const float* __restrict__ ea,
    const int* __restrict__ src, const float* __restrict__ W1,
    const float* __restrict__ b1, unsigned short* __restrict__ gbuf,
    int E, int ntiles)
{
    __shared__ __align__(16) unsigned short wlds[128 * 128];     // 32 KB W1 bf16
    __shared__ __align__(16) unsigned short tlds[4][16 * 128];   // 4x4 KB posE

    const int tid = threadIdx.x;
    const int w = tid >> 6, l = tid & 63, lg = l >> 4, lr = l & 15;

    // ---- cooperative W1 -> LDS (bf16, XOR-swizzled), once per block ----
    for (int j = tid; j < 128 * 32; j += 256) {        // 16B f32 chunks
        const int row = j >> 5, c16 = j & 31;
        f32x4 v = *reinterpret_cast<const f32x4*>(W1 + row * H + c16 * 4);
        u16x4 o;
#pragma unroll
        for (int k = 0; k < 4; ++k) o[k] = f2bfu(v[k]);
        const int col = c16 * 4;
        *reinterpret_cast<u16x4*>(&wlds[row * 128 + (col ^ ((row & 7) << 3))]) = o;
    }
    // bias vectors for accumulator init: b1[ni*16 + lg*4 .. +4]
    f32x4 b1v[8];
#pragma unroll
    for (int ni = 0; ni < 8; ++ni)
        b1v[ni] = *reinterpret_cast<const f32x4*>(b1 + ni * 16 + lg * 4);
    __syncthreads();   // the only barrier; W1 is read-only afterwards

    unsigned short* mylds = &tlds[w][0];
    const int gw = blockIdx.x * 4 + w;       // global wave id
    const int wstride = gridDim.x * 4;

    for (int t = gw; t < ntiles; t += wstride) {
        const int e0 = t * 16;

        // ---- stage 16 rows x 128 f32 -> bf16, coalesced (2 rows/instr) ----
#pragma unroll
        for (int it = 0; it < 8; ++it) {
            const int row = it * 2 + (l >> 5);   // 0..15
            const int c16 = l & 31;
            const int er = e0 + row;
            const int ec = er < E ? er : E - 1;
            const int s = src[ec];
            f32x4 a = *reinterpret_cast<const f32x4*>(ea + (long)ec * H + c16 * 4);
            f32x4 b = *reinterpret_cast<const f32x4*>(x + (long)s * H + c16 * 4);
            u16x4 o;
#pragma unroll
            for (int j = 0; j < 4; ++j) o[j] = f2bfu(a[j] + b[j]);
            const int col = c16 * 4;
            *reinterpret_cast<u16x4*>(&mylds[row * 128 + (col ^ ((row & 7) << 3))]) = o;
        }

        // ---- B fragments (posE, own tile): row lr, k = kk*32+lg*8 ----
        const int aswz = (lr & 7) << 3;
        bf16x8 af[4];
#pragma unroll
        for (int kk = 0; kk < 4; ++kk)
            af[kk] = __builtin_bit_cast(bf16x8,
                *reinterpret_cast<const u16x8*>(&mylds[lr * 128 + ((kk * 32 + lg * 8) ^ aswz)]));

        const int es = e0 + lr;
        const bool ok = es < E;

        // ---- 8 n-tiles x 4 k: A = W1 rows ni*16+lr (from shared LDS) ----
#pragma unroll
        for (int ni = 0; ni < 8; ++ni) {
            const int wrow = ni * 16 + lr;
            const int wswz = (lr & 7) << 3;      // (wrow&7)==(lr&7)
            f32x4 a4 = {b1v[ni][0], b1v[ni][1], b1v[ni][2], b1v[ni][3]};
#pragma unroll
            for (int kk = 0; kk < 4; ++kk) {
                bf16x8 wf = __builtin_bit_cast(bf16x8,
                    *reinterpret_cast<const u16x8*>(&wlds[wrow * 128 + ((kk * 32 + lg * 8) ^ wswz)]));
                a4 = __builtin_amdgcn_mfma_f32_16x16x32_bf16(wf, af[kk], a4, 0, 0, 0);
            }
            if (ok) {
                u16x4 o;
#pragma unroll
                for (int r = 0; r < 4; ++r)
                    o[r] = f2bfu(gelu_fast(a4[r]));
                *reinterpret_cast<u16x4*>(gbuf + (size_t)es * H + ni * 16 + lg * 4) = o;
            }
        }
    }
}

// ---------------------------------------------------------------------------
// Phase B: aggr[n] = sum_{e in group(n)} g[e] * bases[e].
// One wave per node; full-row coalesced reads; random row ORDER only.
// ---------------------------------------------------------------------------
__global__ __launch_bounds__(256) void aggregate_kernel(
    const unsigned short* __restrict__ gbuf, const float* __restrict__ bases,
    const int* __restrict__ perm, const int* __restrict__ offs,
    float* __restrict__ aggr, int Nn, int E)
{
    const int wv = threadIdx.x >> 6, lane = threadIdx.x & 63;
    const int n = blockIdx.x * 4 + wv;
    if (n >= Nn) return;
    const int lo = offs[n], hi = offs[n + 1];
    float a0 = 0.f, a1 = 0.f;
    int i = lo;
    for (; i + 3 < hi; i += 4) {
        int e0 = perm[i], e1 = perm[i + 1], e2 = perm[i + 2], e3 = perm[i + 3];
        e0 = (unsigned)e0 < (unsigned)E ? e0 : 0;
        e1 = (unsigned)e1 < (unsigned)E ? e1 : 0;
        e2 = (unsigned)e2 < (unsigned)E ? e2 : 0;
        e3 = (unsigned)e3 < (unsigned)E ? e3 : 0;
        unsigned u0 = *reinterpret_cast<const unsigned*>(gbuf + (size_t)e0 * H + lane * 2);
        unsigned u1 = *reinterpret_cast<const unsigned*>(gbuf + (size_t)e1 * H + lane * 2);
        unsigned u2 = *reinterpret_cast<const unsigned*>(gbuf + (size_t)e2 * H + lane * 2);
        unsigned u3 = *reinterpret_cast<const unsigned*>(gbuf + (size_t)e3 * H + lane * 2);
        f32x2 b0 = *reinterpret_cast<const f32x2*>(bases + (size_t)e0 * H + lane * 2);
        f32x2 b1_ = *reinterpret_cast<const f32x2*>(bases + (size_t)e1 * H + lane * 2);
        f32x2 b2 = *reinterpret_cast<const f32x2*>(bases + (size_t)e2 * H + lane * 2);
        f32x2 b3 = *reinterpret_cast<const f32x2*>(bases + (size_t)e3 * H + lane * 2);
        a0 += __builtin_bit_cast(float, u0 << 16) * b0[0]
            + __builtin_bit_cast(float, u1 << 16) * b1_[0]
            + __builtin_bit_cast(float, u2 << 16) * b2[0]
            + __builtin_bit_cast(float, u3 << 16) * b3[0];
        a1 += __builtin_bit_cast(float, u0 & 0xffff0000u) * b0[1]
            + __builtin_bit_cast(float, u1 & 0xffff0000u) * b1_[1]
            + __builtin_bit_cast(float, u2 & 0xffff0000u) * b2[1]
            + __builtin_bit_cast(float, u3 & 0xffff0000u) * b3[1];
    }
    for (; i < hi; ++i) {
        int e = perm[i];
        e = (unsigned)e < (unsigned)E ? e : 0;
        unsigned u0 = *reinterpret_cast<const unsigned*>(gbuf + (size_t)e * H + lane * 2);
        f32x2 b0 = *reinterpret_cast<const f32x2*>(bases + (size_t)e * H + lane * 2);
        a0 += __builtin_bit_cast(float, u0 << 16) * b0[0];
        a1 += __builtin_bit_cast(float, u0 & 0xffff0000u) * b0[1];
    }
    f32x2 o = {a0, a1};
    *reinterpret_cast<f32x2*>(aggr + (size_t)n * H + lane * 2) = o;
}

// ---------------------------------------------------------------------------
// Node GEMM  Y = f(A) @ W^T + bias, fused column sum/sumsq epilogue for BN
// stats. PRE=true applies gelu(a*scale+shift) on load.
// ---------------------------------------------------------------------------
template <bool PRE>
__global__ __launch_bounds__(256) void node_gemm(
    const float* __restrict__ A, const float* __restrict__ W,
    const float* __restrict__ bias, const float* __restrict__ scl,
    const float* __restrict__ shf, float* __restrict__ Y,
    float* __restrict__ csum, float* __restrict__ cssq, int Nn)
{
    __shared__ __align__(16) unsigned short alds[64 * 128];

    const int tid = threadIdx.x;
    const int w = tid >> 6, l = tid & 63, lg = l >> 4, lr = l & 15;
    const int er = tid >> 2, q = tid & 3;
    const int r0 = blockIdx.x * 64;

    bf16x8 bf[2][4];
    float bv[2];
#pragma unroll
    for (int n = 0; n < 2; ++n) {
        int row = w * 32 + n * 16 + lr;
        bv[n] = bias[row];
#pragma unroll
        for (int kk = 0; kk < 4; ++kk) {
            const float* p = W + row * H + kk * 32 + lg * 8;
            u16x8 t;
#pragma unroll
            for (int i = 0; i < 8; ++i) t[i] = f2bfu(p[i]);
            bf[n][kk] = __builtin_bit_cast(bf16x8, t);
        }
    }

    {
        int rr = r0 + er;
        int rc = rr < Nn ? rr : Nn - 1;
        const f32x4* pa = reinterpret_cast<const f32x4*>(A + (long)rc * H + q * 32);
        const int swz = (er & 7) << 3;
#pragma unroll
        for (int i = 0; i < 8; ++i) {
            f32x4 v = pa[i];
            if constexpr (PRE) {
                f32x4 sc = *reinterpret_cast<const f32x4*>(scl + q * 32 + i * 4);
                f32x4 sh = *reinterpret_cast<const f32x4*>(shf + q * 32 + i * 4);
#pragma unroll
                for (int c = 0; c < 4; ++c) v[c] = gelu_fast(v[c] * sc[c] + sh[c]);
            }
            u16x4 o;
            o[0] = f2bfu(v[0]);
            o[1] = f2bfu(v[1]);
            o[2] = f2bfu(v[2]);
            o[3] = f2bfu(v[3]);
            int col = q * 32 + i * 4;
            *reinterpret_cast<u16x4*>(&alds[er * 128 + (col ^ swz)]) = o;
        }
    }
    __syncthreads();

    float ps[2] = {0.f, 0.f}, ps2[2] = {0.f, 0.f};
#pragma unroll
    for (int m = 0; m < 4; ++m) {
        const int arow = m * 16 + lr;
        const int aswz = (arow & 7) << 3;
        bf16x8 af[4];
#pragma unroll
        for (int kk = 0; kk < 4; ++kk)
            af[kk] = __builtin_bit_cast(bf16x8,
                *reinterpret_cast<const u16x8*>(&alds[arow * 128 + ((kk * 32 + lg * 8) ^ aswz)]));
#pragma unroll
        for (int n = 0; n < 2; ++n) {
            f32x4 a4 = {0.f, 0.f, 0.f, 0.f};
#pragma unroll
            for (int kk = 0; kk < 4; ++kk)
                a4 = __builtin_amdgcn_mfma_f32_16x16x32_bf16(af[kk], bf[n][kk], a4, 0, 0, 0);
            const int j = w * 32 + n * 16 + lr;
#pragma unroll
            for (int r = 0; r < 4; ++r) {
                int rr = r0 + m * 16 + lg * 4 + r;
                if (rr < Nn) {
                    float z = a4[r] + bv[n];
                    Y[(long)rr * H + j] = z;
                    ps[n] += z;
                    ps2[n] += z * z;
                }
            }
        }
    }
#pragma unroll
    for (int n = 0; n < 2; ++n) {
        float s = ps[n];
        s += __shfl_xor(s, 16);
        s += __shfl_xor(s, 32);
        float s2 = ps2[n];
        s2 += __shfl_xor(s2, 16);
        s2 += __shfl_xor(s2, 32);
        if (lg == 0) {
            int j = w * 32 + n * 16 + lr;
            atomicAdd(&csum[j], s);
            atomicAdd(&cssq[j], s2);
        }
    }
}

__global__ void finalize_bn(const float* __restrict__ csum, const float* __restrict__ cssq,
                            const float* __restrict__ g, const float* __restrict__ be,
                            float* __restrict__ scl, float* __restrict__ shf, float invN)
{
    int j = threadIdx.x;
    float mu = csum[j] * invN;
    float var = fmaxf(cssq[j] * invN - mu * mu, 0.f);
    float s = g[j] * rsqrtf(var + EPS);
    scl[j] = s;
    shf[j] = be[j] - mu * s;
}

__global__ __launch_bounds__(256) void final_gelu(
    const float* __restrict__ Y2, const float* __restrict__ scl,
    const float* __restrict__ shf, float* __restrict__ out, long n4)
{
    long i = (long)blockIdx.x * blockDim.x + threadIdx.x;
    const long stride = (long)gridDim.x * blockDim.x;
    for (; i < n4; i += stride) {
        f32x4 v = reinterpret_cast<const f32x4*>(Y2)[i];
        int c4 = (int)(i & 31);
        f32x4 sc = reinterpret_cast<const f32x4*>(scl)[c4];
        f32x4 sh = reinterpret_cast<const f32x4*>(shf)[c4];
        f32x4 o;
#pragma unroll
        for (int c = 0; c < 4; ++c) o[c] = gelu_fast(v[c] * sc[c] + sh[c]);
        reinterpret_cast<f32x4*>(out)[i] = o;
    }
}

extern "C" void kernel_launch(void* const* d_in, const int* in_sizes, int n_in,
                              void* d_out, int out_size, void* d_ws, size_t ws_size,
                              hipStream_t stream) {
    const float* x     = (const float*)d_in[0];
    const float* ea    = (const float*)d_in[1];
    const float* bases = (const float*)d_in[2];
    const int*   src   = (const int*)d_in[3];
    const int*   dst   = (const int*)d_in[4];
    const float* W1    = (const float*)d_in[5];
    const float* b1    = (const float*)d_in[6];
    const float* W2    = (const float*)d_in[7];
    const float* b2    = (const float*)d_in[8];
    const float* g1    = (const float*)d_in[9];
    const float* be1   = (const float*)d_in[10];
    const float* W3    = (const float*)d_in[11];
    const float* b3    = (const float*)d_in[12];
    const float* g2    = (const float*)d_in[13];
    const float* be2   = (const float*)d_in[14];

    const int N = in_sizes[0] / H;
    const int E = in_sizes[1] / H;

    float* ws    = (float*)d_ws;
    float* aggr  = ws;                        // [N,H]; reused as y2
    float* y1    = aggr + (size_t)N * H;      // [N,H]
    float* stats = y1 + (size_t)N * H;        // 1024 floats
    float* sum1 = stats,        *ss1 = stats + 128;
    float* sum2 = stats + 256,  *ss2 = stats + 384;
    float* scl1 = stats + 512,  *shf1 = stats + 640;
    float* scl2 = stats + 768,  *shf2 = stats + 896;
    int* cnt  = (int*)(stats + 1024);         // [N] histogram
    int* cnt2 = cnt + N;                      // [N] scatter cursor (zeroed)
    int* perm = cnt2 + N;                     // [E]
    int* offs = perm + E;                     // [N+1]
    unsigned short* gbuf = (unsigned short*)(((uintptr_t)(offs + N + 1) + 4095) & ~(uintptr_t)4095); // [E,H] bf16

    // zero stats (1024 f32) + cnt (N) + cnt2 (N)
    const int zn4 = (1024 + 2 * N + 3) / 4;
    zero_kernel<<<128, 256, 0, stream>>>((int*)stats, zn4);

    // --- counting sort (perm + offs) ---
    hist_kernel<<<2048, 256, 0, stream>>>(dst, cnt, E);
    scan_kernel<<<1, 1024, 0, stream>>>(cnt, offs, N, E);
    scatter_perm<<<2048, 256, 0, stream>>>(dst, offs, cnt2, perm, E);

    // --- Phase A: wave-private fused edge MLP (no per-tile barrier) ---
    const int ntiles = (E + 15) / 16;
    fused_edge<<<2048, 256, 0, stream>>>(x, ea, src, W1, b1, gbuf, E, ntiles);

    // --- Phase B: aggr = segment-sum(g * bases) via perm gather ---
    aggregate_kernel<<<(N + 3) / 4, 256, 0, stream>>>(gbuf, bases, perm, offs, aggr, N, E);

    // --- node pipeline ---
    const int nblk = (N + 63) / 64;
    node_gemm<false><<<nblk, 256, 0, stream>>>(aggr, W2, b2, nullptr, nullptr, y1, sum1, ss1, N);
    finalize_bn<<<1, 128, 0, stream>>>(sum1, ss1, g1, be1, scl1, shf1, 1.0f / (float)N);
    node_gemm<true><<<nblk, 256, 0, stream>>>(y1, W3, b3, scl1, shf1, aggr, sum2, ss2, N);
    finalize_bn<<<1, 128, 0, stream>>>(sum2, ss2, g2, be2, scl2, shf2, 1.0f / (float)N);

    long n4 = (long)N * H / 4;
    final_gelu<<<2048, 256, 0, stream>>>(aggr, scl2, shf2, (float*)d_out, n4);
}

// Round 11
// 499.842 us; speedup vs baseline: 1.1509x; 1.1509x over previous
//
#include <hip/hip_runtime.h>
#include <cmath>

#define H 128
#define EPS 1e-5f

typedef __attribute__((ext_vector_type(8))) __bf16 bf16x8;
typedef __attribute__((ext_vector_type(4))) float f32x4;
typedef __attribute__((ext_vector_type(2))) float f32x2;
typedef __attribute__((ext_vector_type(4))) unsigned short u16x4;
typedef __attribute__((ext_vector_type(8))) unsigned short u16x8;
typedef __attribute__((ext_vector_type(4))) int i32x4;

// Fast GELU (sigmoid form), ~7 VALU ops; max abs err ~1e-3 (below bf16
// rounding of the result). Verified R9: absmax unchanged vs erff.
__device__ __forceinline__ float gelu_fast(float x) {
    float t2 = -1.5957691216057308f * fmaf(0.044715f * x * x, x, x); // -2t
    return x * __builtin_amdgcn_rcpf(1.0f + __expf(t2));
}

__device__ __forceinline__ unsigned short f2bfu(float f) {
    __bf16 h = (__bf16)f;   // RNE fptrunc
    return __builtin_bit_cast(unsigned short, h);
}

__device__ __forceinline__ float bfu2f(unsigned short u) {
    return __builtin_bit_cast(float, (unsigned)u << 16);
}

// ---------------------------------------------------------------------------
// Zero scratch — in-graph hipMemsetAsync measured 195us for 324 KB (R7).
// ---------------------------------------------------------------------------
__global__ __launch_bounds__(256) void zero_kernel(int* __restrict__ p, int n4)
{
    int i = blockIdx.x * blockDim.x + threadIdx.x;
    const int stride = gridDim.x * blockDim.x;
    i32x4 z = {0, 0, 0, 0};
    for (; i < n4; i += stride)
        reinterpret_cast<i32x4*>(p)[i] = z;
}

// ---------------------------------------------------------------------------
// Counting sort of edges by dst -> perm (dst-grouped edge ids), dsts (node
// id per sorted position), offs.
// ---------------------------------------------------------------------------
__global__ __launch_bounds__(256) void hist_kernel(const int* __restrict__ dst,
                                                   int* __restrict__ cnt, int E)
{
    int i = blockIdx.x * blockDim.x + threadIdx.x;
    const int stride = gridDim.x * blockDim.x;
    for (; i < E; i += stride) atomicAdd(&cnt[dst[i]], 1);
}

__global__ __launch_bounds__(1024) void scan_kernel(const int* __restrict__ cnt,
                                                    int* __restrict__ offs,
                                                    int Nn, int E)
{
    __shared__ int part[1024];
    const int t = threadIdx.x;
    const int CH = (Nn + 1023) / 1024;
    const int base = t * CH;
    int s = 0;
    for (int i = 0; i < CH; ++i) {
        int idx = base + i;
        if (idx < Nn) s += cnt[idx];
    }
    part[t] = s;
    __syncthreads();
    for (int d = 1; d < 1024; d <<= 1) {
        int v = (t >= d) ? part[t - d] : 0;
        __syncthreads();
        part[t] += v;
        __syncthreads();
    }
    int run = (t > 0) ? part[t - 1] : 0;
    for (int i = 0; i < CH; ++i) {
        int idx = base + i;
        if (idx < Nn) {
            offs[idx] = run;
            run += cnt[idx];
        }
    }
    if (t == 0) offs[Nn] = E;
}

__global__ __launch_bounds__(256) void scatter_perm(const int* __restrict__ dst,
                                                    const int* __restrict__ offs,
                                                    int* __restrict__ cur2,
                                                    int* __restrict__ perm,
                                                    int* __restrict__ dsts, int E)
{
    int i = blockIdx.x * blockDim.x + threadIdx.x;
    const int stride = gridDim.x * blockDim.x;
    for (; i < E; i += stride) {
        int n = dst[i];
        int p = offs[n] + atomicAdd(&cur2[n], 1);
        perm[p] = i;
        dsts[p] = n;
    }
}

// ---------------------------------------------------------------------------
// FULLY-FUSED edge phase over dst-sorted edges:
//   aggr[n] += sum over the node's edges of gelu((x[src]+ea)@W1^T + b1)*bases
// One 64-edge (sorted) tile per block. Staging is full-line coalesced
// (chunk id -> 2 complete 512B rows per instruction) for ea AND bases,
// gathered via perm. Swapped-operand MFMA (bias folded into C-init) gives
// lane (lg,lr) -> [cols w*32+ni*16+lg*4..+4][edge s*16+lr]. v = gelu*bases
// in f32, then a Kogge-Stone SEGMENTED shuffle reduction across the 16-lane
// edge dimension (dst-sorted => segments contiguous); head lanes atomicAdd
// into aggr (runs spanning groups/tiles just produce partial sums).
// ---------------------------------------------------------------------------
__global__ __launch_bounds__(256) void edge_aggr(
    const float* __restrict__ x, const float* __restrict__ ea,
    const float* __restrict__ bases, const int* __restrict__ src,
    const int* __restrict__ perm, const int* __restrict__ dsts,
    const float* __restrict__ W1, const float* __restrict__ b1,
    float* __restrict__ aggr, int E)
{
    __shared__ __align__(16) unsigned short alds[64 * 128];  // posE bf16, 16 KB
    __shared__ __align__(16) unsigned short blds[64 * 128];  // bases bf16, 16 KB
    __shared__ int nd_lds[64];

    const int tid = threadIdx.x;
    const int w = tid >> 6, l = tid & 63, lg = l >> 4, lr = l & 15;

    // W1 A-fragments: rows w*32 + ni*16 + lr, k = kk*32 + lg*8 .. +8
    bf16x8 wf[2][4];
    f32x4 b1v[2];
#pragma unroll
    for (int ni = 0; ni < 2; ++ni) {
        int row = w * 32 + ni * 16 + lr;
#pragma unroll
        for (int kk = 0; kk < 4; ++kk) {
            const float* p = W1 + row * H + kk * 32 + lg * 8;
            u16x8 tt;
#pragma unroll
            for (int i = 0; i < 8; ++i) tt[i] = f2bfu(p[i]);
            wf[ni][kk] = __builtin_bit_cast(bf16x8, tt);
        }
        b1v[ni] = *reinterpret_cast<const f32x4*>(b1 + w * 32 + ni * 16 + lg * 4);
    }

    const int e0 = blockIdx.x * 64;
    if (tid < 64) {
        int i = e0 + tid;
        nd_lds[tid] = dsts[i < E ? i : E - 1];
    }

    // ---- stage: 64 sorted edges x 128 cols, coalesced (2 rows/instr) ----
#pragma unroll
    for (int it = 0; it < 8; ++it) {
        const int gch = it * 256 + tid;      // 16B f32 chunk id, 0..2047
        const int row = gch >> 5;            // sorted position within tile
        const int c16 = gch & 31;
        const int ip = e0 + row;
        const int ic = ip < E ? ip : E - 1;
        const int e = perm[ic];              // broadcast across 32 lanes
        const int s = src[e];
        f32x4 a = *reinterpret_cast<const f32x4*>(ea + (long)e * H + c16 * 4);
        f32x4 b = *reinterpret_cast<const f32x4*>(x + (long)s * H + c16 * 4);
        f32x4 bs = *reinterpret_cast<const f32x4*>(bases + (long)e * H + c16 * 4);
        u16x4 o, ob;
#pragma unroll
        for (int j = 0; j < 4; ++j) { o[j] = f2bfu(a[j] + b[j]); ob[j] = f2bfu(bs[j]); }
        const int scol = (c16 * 4) ^ ((row & 7) << 3);
        *reinterpret_cast<u16x4*>(&alds[row * 128 + scol]) = o;
        *reinterpret_cast<u16x4*>(&blds[row * 128 + scol]) = ob;
    }
    __syncthreads();

    // ---- compute + in-register segmented reduction + atomic epilogue ----
    const int col0base = w * 32 + lg * 4;
#pragma unroll
    for (int s = 0; s < 4; ++s) {
        const int arow = s * 16 + lr;
        const int aswz = (arow & 7) << 3;
        bf16x8 af[4];
#pragma unroll
        for (int kk = 0; kk < 4; ++kk)
            af[kk] = __builtin_bit_cast(bf16x8,
                *reinterpret_cast<const u16x8*>(&alds[arow * 128 + ((kk * 32 + lg * 8) ^ aswz)]));

        const int es = e0 + arow;
        const bool ok = es < E;
        const int nd = nd_lds[arow];
        const bool head = ok && (lr == 0 || nd != nd_lds[arow - 1]);

#pragma unroll
        for (int ni = 0; ni < 2; ++ni) {
            f32x4 a4 = b1v[ni];   // bias as C-init
#pragma unroll
            for (int kk = 0; kk < 4; ++kk)
                a4 = __builtin_amdgcn_mfma_f32_16x16x32_bf16(wf[ni][kk], af[kk], a4, 0, 0, 0);

            const int col0 = col0base + ni * 16;
            u16x4 bq = *reinterpret_cast<const u16x4*>(&blds[arow * 128 + (col0 ^ aswz)]);
            f32x4 v;
#pragma unroll
            for (int r = 0; r < 4; ++r)
                v[r] = ok ? gelu_fast(a4[r]) * bfu2f(bq[r]) : 0.f;

            // Kogge-Stone segmented suffix-sum across lr (16-lane groups)
#pragma unroll
            for (int d = 1; d < 16; d <<= 1) {
                f32x4 vn;
#pragma unroll
                for (int r = 0; r < 4; ++r) vn[r] = __shfl_down(v[r], d);
                int ndn = __shfl_down(nd, d);
                bool take = (lr + d < 16) && (ndn == nd);
#pragma unroll
                for (int r = 0; r < 4; ++r) v[r] += take ? vn[r] : 0.f;
            }

            if (head) {
                float* dst = aggr + (long)nd * H + col0;
#pragma unroll
                for (int r = 0; r < 4; ++r) atomicAdd(&dst[r], v[r]);
            }
        }
    }
}

// ---------------------------------------------------------------------------
// Node GEMM  Y = f(A) @ W^T + bias, fused column sum/sumsq epilogue for BN
// stats. PRE=true applies gelu(a*scale+shift) on load.
// ---------------------------------------------------------------------------
template <bool PRE>
__global__ __launch_bounds__(256) void node_gemm(
    const float* __restrict__ A, const float* __restrict__ W,
    const float* __restrict__ bias, const float* __restrict__ scl,
    const float* __restrict__ shf, float* __restrict__ Y,
    float* __restrict__ csum, float* __restrict__ cssq, int Nn)
{
    __shared__ __align__(16) unsigned short alds[64 * 128];

    const int tid = threadIdx.x;
    const int w = tid >> 6, l = tid & 63, lg = l >> 4, lr = l & 15;
    const int er = tid >> 2, q = tid & 3;
    const int r0 = blockIdx.x * 64;

    bf16x8 bf[2][4];
    float bv[2];
#pragma unroll
    for (int n = 0; n < 2; ++n) {
        int row = w * 32 + n * 16 + lr;
        bv[n] = bias[row];
#pragma unroll
        for (int kk = 0; kk < 4; ++kk) {
            const float* p = W + row * H + kk * 32 + lg * 8;
            u16x8 t;
#pragma unroll
            for (int i = 0; i < 8; ++i) t[i] = f2bfu(p[i]);
            bf[n][kk] = __builtin_bit_cast(bf16x8, t);
        }
    }

    {
        int rr = r0 + er;
        int rc = rr < Nn ? rr : Nn - 1;
        const f32x4* pa = reinterpret_cast<const f32x4*>(A + (long)rc * H + q * 32);
        const int swz = (er & 7) << 3;
#pragma unroll
        for (int i = 0; i < 8; ++i) {
            f32x4 v = pa[i];
            if constexpr (PRE) {
                f32x4 sc = *reinterpret_cast<const f32x4*>(scl + q * 32 + i * 4);
                f32x4 sh = *reinterpret_cast<const f32x4*>(shf + q * 32 + i * 4);
#pragma unroll
                for (int c = 0; c < 4; ++c) v[c] = gelu_fast(v[c] * sc[c] + sh[c]);
            }
            u16x4 o;
            o[0] = f2bfu(v[0]);
            o[1] = f2bfu(v[1]);
            o[2] = f2bfu(v[2]);
            o[3] = f2bfu(v[3]);
            int col = q * 32 + i * 4;
            *reinterpret_cast<u16x4*>(&alds[er * 128 + (col ^ swz)]) = o;
        }
    }
    __syncthreads();

    float ps[2] = {0.f, 0.f}, ps2[2] = {0.f, 0.f};
#pragma unroll
    for (int m = 0; m < 4; ++m) {
        const int arow = m * 16 + lr;
        const int aswz = (arow & 7) << 3;
        bf16x8 af[4];
#pragma unroll
        for (int kk = 0; kk < 4; ++kk)
            af[kk] = __builtin_bit_cast(bf16x8,
                *reinterpret_cast<const u16x8*>(&alds[arow * 128 + ((kk * 32 + lg * 8) ^ aswz)]));
#pragma unroll
        for (int n = 0; n < 2; ++n) {
            f32x4 a4 = {0.f, 0.f, 0.f, 0.f};
#pragma unroll
            for (int kk = 0; kk < 4; ++kk)
                a4 = __builtin_amdgcn_mfma_f32_16x16x32_bf16(af[kk], bf[n][kk], a4, 0, 0, 0);
            const int j = w * 32 + n * 16 + lr;
#pragma unroll
            for (int r = 0; r < 4; ++r) {
                int rr = r0 + m * 16 + lg * 4 + r;
                if (rr < Nn) {
                    float z = a4[r] + bv[n];
                    Y[(long)rr * H + j] = z;
                    ps[n] += z;
                    ps2[n] += z * z;
                }
            }
        }
    }
#pragma unroll
    for (int n = 0; n < 2; ++n) {
        float s = ps[n];
        s += __shfl_xor(s, 16);
        s += __shfl_xor(s, 32);
        float s2 = ps2[n];
        s2 += __shfl_xor(s2, 16);
        s2 += __shfl_xor(s2, 32);
        if (lg == 0) {
            int j = w * 32 + n * 16 + lr;
            atomicAdd(&csum[j], s);
            atomicAdd(&cssq[j], s2);
        }
    }
}

__global__ void finalize_bn(const float* __restrict__ csum, const float* __restrict__ cssq,
                            const float* __restrict__ g, const float* __restrict__ be,
                            float* __restrict__ scl, float* __restrict__ shf, float invN)
{
    int j = threadIdx.x;
    float mu = csum[j] * invN;
    float var = fmaxf(cssq[j] * invN - mu * mu, 0.f);
    float s = g[j] * rsqrtf(var + EPS);
    scl[j] = s;
    shf[j] = be[j] - mu * s;
}

__global__ __launch_bounds__(256) void final_gelu(
    const float* __restrict__ Y2, const float* __restrict__ scl,
    const float* __restrict__ shf, float* __restrict__ out, long n4)
{
    long i = (long)blockIdx.x * blockDim.x + threadIdx.x;
    const long stride = (long)gridDim.x * blockDim.x;
    for (; i < n4; i += stride) {
        f32x4 v = reinterpret_cast<const f32x4*>(Y2)[i];
        int c4 = (int)(i & 31);
        f32x4 sc = reinterpret_cast<const f32x4*>(scl)[c4];
        f32x4 sh = reinterpret_cast<const f32x4*>(shf)[c4];
        f32x4 o;
#pragma unroll
        for (int c = 0; c < 4; ++c) o[c] = gelu_fast(v[c] * sc[c] + sh[c]);
        reinterpret_cast<f32x4*>(out)[i] = o;
    }
}

extern "C" void kernel_launch(void* const* d_in, const int* in_sizes, int n_in,
                              void* d_out, int out_size, void* d_ws, size_t ws_size,
                              hipStream_t stream) {
    const float* x     = (const float*)d_in[0];
    const float* ea    = (const float*)d_in[1];
    const float* bases = (const float*)d_in[2];
    const int*   src   = (const int*)d_in[3];
    const int*   dst   = (const int*)d_in[4];
    const float* W1    = (const float*)d_in[5];
    const float* b1    = (const float*)d_in[6];
    const float* W2    = (const float*)d_in[7];
    const float* b2    = (const float*)d_in[8];
    const float* g1    = (const float*)d_in[9];
    const float* be1   = (const float*)d_in[10];
    const float* W3    = (const float*)d_in[11];
    const float* b3    = (const float*)d_in[12];
    const float* g2    = (const float*)d_in[13];
    const float* be2   = (const float*)d_in[14];

    const int N = in_sizes[0] / H;
    const int E = in_sizes[1] / H;

    float* ws    = (float*)d_ws;
    float* aggr  = ws;                        // [N,H]; reused as y2
    float* y1    = aggr + (size_t)N * H;      // [N,H]
    float* stats = y1 + (size_t)N * H;        // 1024 floats
    float* sum1 = stats,        *ss1 = stats + 128;
    float* sum2 = stats + 256,  *ss2 = stats + 384;
    float* scl1 = stats + 512,  *shf1 = stats + 640;
    float* scl2 = stats + 768,  *shf2 = stats + 896;
    int* cnt  = (int*)(stats + 1024);         // [N] histogram
    int* cnt2 = cnt + N;                      // [N] scatter cursor (zeroed)
    int* perm = cnt2 + N;                     // [E]
    int* dsts = perm + E;                     // [E] node id per sorted pos
    int* offs = dsts + E;                     // [N+1]

    // zero stats + cnt + cnt2, and aggr (atomic accumulation target)
    const int zn4 = (1024 + 2 * N + 3) / 4;
    zero_kernel<<<128, 256, 0, stream>>>((int*)stats, zn4);
    zero_kernel<<<1024, 256, 0, stream>>>((int*)aggr, N * H / 4);

    // --- counting sort (perm + dsts + offs) ---
    hist_kernel<<<2048, 256, 0, stream>>>(dst, cnt, E);
    scan_kernel<<<1, 1024, 0, stream>>>(cnt, offs, N, E);
    scatter_perm<<<2048, 256, 0, stream>>>(dst, offs, cnt2, perm, dsts, E);

    // --- fully-fused edge phase: GEMM + gelu + *bases + segment-sum ---
    edge_aggr<<<(E + 63) / 64, 256, 0, stream>>>(x, ea, bases, src, perm, dsts,
                                                 W1, b1, aggr, E);

    // --- node pipeline ---
    const int nblk = (N + 63) / 64;
    node_gemm<false><<<nblk, 256, 0, stream>>>(aggr, W2, b2, nullptr, nullptr, y1, sum1, ss1, N);
    finalize_bn<<<1, 128, 0, stream>>>(sum1, ss1, g1, be1, scl1, shf1, 1.0f / (float)N);
    node_gemm<true><<<nblk, 256, 0, stream>>>(y1, W3, b3, scl1, shf1, aggr, sum2, ss2, N);
    finalize_bn<<<1, 128, 0, stream>>>(sum2, ss2, g2, be2, scl2, shf2, 1.0f / (float)N);

    long n4 = (long)N * H / 4;
    final_gelu<<<2048, 256, 0, stream>>>(aggr, scl2, shf2, (float*)d_out, n4);
}

// Round 12
// 463.286 us; speedup vs baseline: 1.2418x; 1.0789x over previous
//
#include <hip/hip_runtime.h>
#include <cmath>

#define H 128
#define EPS 1e-5f

typedef __attribute__((ext_vector_type(8))) __bf16 bf16x8;
typedef __attribute__((ext_vector_type(4))) float f32x4;
typedef __attribute__((ext_vector_type(2))) float f32x2;
typedef __attribute__((ext_vector_type(4))) unsigned short u16x4;
typedef __attribute__((ext_vector_type(8))) unsigned short u16x8;
typedef __attribute__((ext_vector_type(4))) int i32x4;

// Fast GELU (sigmoid form); verified R9: absmax unchanged vs erff.
__device__ __forceinline__ float gelu_fast(float x) {
    float t2 = -1.5957691216057308f * fmaf(0.044715f * x * x, x, x); // -2t
    return x * __builtin_amdgcn_rcpf(1.0f + __expf(t2));
}

__device__ __forceinline__ unsigned short f2bfu(float f) {
    __bf16 h = (__bf16)f;   // RNE fptrunc
    return __builtin_bit_cast(unsigned short, h);
}

__device__ __forceinline__ float bfu2f(unsigned short u) {
    return __builtin_bit_cast(float, (unsigned)u << 16);
}

// async global -> LDS, 16B per lane (lane i lands at ldsbase + i*16).
// ldsbase must be wave-uniform; global address is per-lane.
__device__ __forceinline__ void gld16(const void* g, void* l) {
    __builtin_amdgcn_global_load_lds(
        (__attribute__((address_space(1))) void*)(g),
        (__attribute__((address_space(3))) void*)(l), 16, 0, 0);
}

// ---------------------------------------------------------------------------
// Zero scratch — in-graph hipMemsetAsync measured 195us for 324 KB (R7).
// ---------------------------------------------------------------------------
__global__ __launch_bounds__(256) void zero_kernel(int* __restrict__ p, int n4)
{
    int i = blockIdx.x * blockDim.x + threadIdx.x;
    const int stride = gridDim.x * blockDim.x;
    i32x4 z = {0, 0, 0, 0};
    for (; i < n4; i += stride)
        reinterpret_cast<i32x4*>(p)[i] = z;
}

// ---------------------------------------------------------------------------
// Counting sort of edges by dst -> perm (dst-grouped edge ids), dsts, offs.
// ---------------------------------------------------------------------------
__global__ __launch_bounds__(256) void hist_kernel(const int* __restrict__ dst,
                                                   int* __restrict__ cnt, int E)
{
    int i = blockIdx.x * blockDim.x + threadIdx.x;
    const int stride = gridDim.x * blockDim.x;
    for (; i < E; i += stride) atomicAdd(&cnt[dst[i]], 1);
}

__global__ __launch_bounds__(1024) void scan_kernel(const int* __restrict__ cnt,
                                                    int* __restrict__ offs,
                                                    int Nn, int E)
{
    __shared__ int part[1024];
    const int t = threadIdx.x;
    const int CH = (Nn + 1023) / 1024;
    const int base = t * CH;
    int s = 0;
    for (int i = 0; i < CH; ++i) {
        int idx = base + i;
        if (idx < Nn) s += cnt[idx];
    }
    part[t] = s;
    __syncthreads();
    for (int d = 1; d < 1024; d <<= 1) {
        int v = (t >= d) ? part[t - d] : 0;
        __syncthreads();
        part[t] += v;
        __syncthreads();
    }
    int run = (t > 0) ? part[t - 1] : 0;
    for (int i = 0; i < CH; ++i) {
        int idx = base + i;
        if (idx < Nn) {
            offs[idx] = run;
            run += cnt[idx];
        }
    }
    if (t == 0) offs[Nn] = E;
}

__global__ __launch_bounds__(256) void scatter_perm(const int* __restrict__ dst,
                                                    const int* __restrict__ offs,
                                                    int* __restrict__ cur2,
                                                    int* __restrict__ perm,
                                                    int* __restrict__ dsts, int E)
{
    int i = blockIdx.x * blockDim.x + threadIdx.x;
    const int stride = gridDim.x * blockDim.x;
    for (; i < E; i += stride) {
        int n = dst[i];
        int p = offs[n] + atomicAdd(&cur2[n], 1);
        perm[p] = i;
        dsts[p] = n;
    }
}

// ---------------------------------------------------------------------------
// FULLY-FUSED edge phase over dst-sorted edges (R11 structure), staging
// rebuilt around async global_load_lds:
//  - ea, bases: raw f32 -> LDS via gld16 (8 async instrs/stream/wave, zero
//    VGPR). Source chunk index pre-XOR'd with (row&7) so the linear LDS +
//    swizzled ds_read is bank-conflict-free.
//  - x (L3-resident): reg-staged to bf16 LDS (R11 path).
//  - tile metadata (perm/src/dsts) per-lane in registers, __shfl to fetch.
// posE = ea + x assembled at fragment-build time; bases consumed in f32.
// ---------------------------------------------------------------------------
__global__ __launch_bounds__(256, 2) void edge_aggr(
    const float* __restrict__ x, const float* __restrict__ ea,
    const float* __restrict__ bases, const int* __restrict__ src,
    const int* __restrict__ perm, const int* __restrict__ dsts,
    const float* __restrict__ W1, const float* __restrict__ b1,
    float* __restrict__ aggr, int E)
{
    __shared__ __align__(16) float ealds[64 * 128];            // 32 KB f32
    __shared__ __align__(16) float blds[64 * 128];             // 32 KB f32
    __shared__ __align__(16) unsigned short xlds[64 * 128];    // 16 KB bf16

    const int tid = threadIdx.x;
    const int w = tid >> 6, l = tid & 63, lg = l >> 4, lr = l & 15;

    // W1 A-fragments: rows w*32 + ni*16 + lr, k = kk*32 + lg*8 .. +8
    bf16x8 wf[2][4];
    f32x4 b1v[2];
#pragma unroll
    for (int ni = 0; ni < 2; ++ni) {
        int row = w * 32 + ni * 16 + lr;
#pragma unroll
        for (int kk = 0; kk < 4; ++kk) {
            const float* p = W1 + row * H + kk * 32 + lg * 8;
            u16x8 tt;
#pragma unroll
            for (int i = 0; i < 8; ++i) tt[i] = f2bfu(p[i]);
            wf[ni][kk] = __builtin_bit_cast(bf16x8, tt);
        }
        b1v[ni] = *reinterpret_cast<const f32x4*>(b1 + w * 32 + ni * 16 + lg * 4);
    }

    const int e0 = blockIdx.x * 64;
    // per-lane tile metadata: lane l <-> sorted position e0+l (all 4 waves
    // redundantly hold all 64 rows -> __shfl replaces LDS arrays)
    int ic = e0 + l;
    ic = ic < E ? ic : E - 1;
    const int el_reg = perm[ic];
    const int nd_reg = dsts[ic];
    const int sr_reg = src[el_reg];

    // ---- issue async ea + bases staging (f32, source-swizzled) ----
#pragma unroll
    for (int j = 0; j < 8; ++j) {
        const int r = (w << 4) + (j << 1) + (l >> 5);   // row 0..63
        const int e = __shfl(el_reg, r);
        const int cs = (l & 31) ^ (r & 7);              // 16B-chunk, pre-swizzled
        const int rowbase = (((w << 4) + (j << 1)) << 7);  // floats
        gld16(ea + (long)e * H + cs * 4, &ealds[rowbase]);
        gld16(bases + (long)e * H + cs * 4, &blds[rowbase]);
    }

    // ---- x reg-staged to bf16 LDS (XOR swizzle on bf16 cols) ----
#pragma unroll
    for (int it = 0; it < 8; ++it) {
        const int gch = it * 256 + tid;
        const int row = gch >> 5, c16 = gch & 31;
        const int s = __shfl(sr_reg, row);
        f32x4 b = *reinterpret_cast<const f32x4*>(x + (long)s * H + c16 * 4);
        u16x4 o;
#pragma unroll
        for (int j = 0; j < 4; ++j) o[j] = f2bfu(b[j]);
        const int scol = (c16 * 4) ^ ((row & 7) << 3);
        *reinterpret_cast<u16x4*>(&xlds[row * 128 + scol]) = o;
    }
    __syncthreads();   // drains vmcnt (incl. global_load_lds) + lgkm

    // ---- compute + in-register segmented reduction + atomic epilogue ----
    const int col0base = w * 32 + lg * 4;
#pragma unroll
    for (int s = 0; s < 4; ++s) {
        const int arow = s * 16 + lr;
        const int fswz = arow & 7;            // f32 16B-chunk XOR
        const int xswz = fswz << 3;           // bf16 col XOR

        // posE fragments: ea (f32 LDS) + x (bf16 LDS) -> bf16 pack
        bf16x8 af[4];
#pragma unroll
        for (int kk = 0; kk < 4; ++kk) {
            const int cc = kk * 8 + lg * 2;
            f32x4 elo = *reinterpret_cast<const f32x4*>(&ealds[arow * 128 + ((cc ^ fswz) << 2)]);
            f32x4 ehi = *reinterpret_cast<const f32x4*>(&ealds[arow * 128 + (((cc + 1) ^ fswz) << 2)]);
            u16x8 xv = *reinterpret_cast<const u16x8*>(&xlds[arow * 128 + ((kk * 32 + lg * 8) ^ xswz)]);
            u16x8 o;
#pragma unroll
            for (int r = 0; r < 4; ++r) {
                o[r]     = f2bfu(elo[r] + bfu2f(xv[r]));
                o[r + 4] = f2bfu(ehi[r] + bfu2f(xv[r + 4]));
            }
            af[kk] = __builtin_bit_cast(bf16x8, o);
        }

        const int es = e0 + arow;
        const bool ok = es < E;
        const int nd = __shfl(nd_reg, arow);
        const int ndp = __shfl(nd_reg, arow - 1);   // arow==0 masked by lr==0
        const bool head = ok && (lr == 0 || nd != ndp);

#pragma unroll
        for (int ni = 0; ni < 2; ++ni) {
            f32x4 a4 = b1v[ni];   // bias as C-init
#pragma unroll
            for (int kk = 0; kk < 4; ++kk)
                a4 = __builtin_amdgcn_mfma_f32_16x16x32_bf16(wf[ni][kk], af[kk], a4, 0, 0, 0);

            const int col0 = col0base + ni * 16;
            const int bcc = col0 >> 2;
            f32x4 bq = *reinterpret_cast<const f32x4*>(&blds[arow * 128 + ((bcc ^ fswz) << 2)]);
            f32x4 v;
#pragma unroll
            for (int r = 0; r < 4; ++r)
                v[r] = ok ? gelu_fast(a4[r]) * bq[r] : 0.f;

            // Kogge-Stone segmented suffix-sum across lr (16-lane groups)
#pragma unroll
            for (int d = 1; d < 16; d <<= 1) {
                f32x4 vn;
#pragma unroll
                for (int r = 0; r < 4; ++r) vn[r] = __shfl_down(v[r], d);
                int ndn = __shfl_down(nd, d);
                bool take = (lr + d < 16) && (ndn == nd);
#pragma unroll
                for (int r = 0; r < 4; ++r) v[r] += take ? vn[r] : 0.f;
            }

            if (head) {
                float* dstp = aggr + (long)nd * H + col0;
#pragma unroll
                for (int r = 0; r < 4; ++r) atomicAdd(&dstp[r], v[r]);
            }
        }
    }
}

// ---------------------------------------------------------------------------
// Node GEMM  Y = f(A) @ W^T + bias, fused column sum/sumsq epilogue for BN
// stats. PRE=true applies gelu(a*scale+shift) on load.
// ---------------------------------------------------------------------------
template <bool PRE>
__global__ __launch_bounds__(256) void node_gemm(
    const float* __restrict__ A, const float* __restrict__ W,
    const float* __restrict__ bias, const float* __restrict__ scl,
    const float* __restrict__ shf, float* __restrict__ Y,
    float* __restrict__ csum, float* __restrict__ cssq, int Nn)
{
    __shared__ __align__(16) unsigned short alds[64 * 128];

    const int tid = threadIdx.x;
    const int w = tid >> 6, l = tid & 63, lg = l >> 4, lr = l & 15;
    const int er = tid >> 2, q = tid & 3;
    const int r0 = blockIdx.x * 64;

    bf16x8 bf[2][4];
    float bv[2];
#pragma unroll
    for (int n = 0; n < 2; ++n) {
        int row = w * 32 + n * 16 + lr;
        bv[n] = bias[row];
#pragma unroll
        for (int kk = 0; kk < 4; ++kk) {
            const float* p = W + row * H + kk * 32 + lg * 8;
            u16x8 t;
#pragma unroll
            for (int i = 0; i < 8; ++i) t[i] = f2bfu(p[i]);
            bf[n][kk] = __builtin_bit_cast(bf16x8, t);
        }
    }

    {
        int rr = r0 + er;
        int rc = rr < Nn ? rr : Nn - 1;
        const f32x4* pa = reinterpret_cast<const f32x4*>(A + (long)rc * H + q * 32);
        const int swz = (er & 7) << 3;
#pragma unroll
        for (int i = 0; i < 8; ++i) {
            f32x4 v = pa[i];
            if constexpr (PRE) {
                f32x4 sc = *reinterpret_cast<const f32x4*>(scl + q * 32 + i * 4);
                f32x4 sh = *reinterpret_cast<const f32x4*>(shf + q * 32 + i * 4);
#pragma unroll
                for (int c = 0; c < 4; ++c) v[c] = gelu_fast(v[c] * sc[c] + sh[c]);
            }
            u16x4 o;
            o[0] = f2bfu(v[0]);
            o[1] = f2bfu(v[1]);
            o[2] = f2bfu(v[2]);
            o[3] = f2bfu(v[3]);
            int col = q * 32 + i * 4;
            *reinterpret_cast<u16x4*>(&alds[er * 128 + (col ^ swz)]) = o;
        }
    }
    __syncthreads();

    float ps[2] = {0.f, 0.f}, ps2[2] = {0.f, 0.f};
#pragma unroll
    for (int m = 0; m < 4; ++m) {
        const int arow = m * 16 + lr;
        const int aswz = (arow & 7) << 3;
        bf16x8 af[4];
#pragma unroll
        for (int kk = 0; kk < 4; ++kk)
            af[kk] = __builtin_bit_cast(bf16x8,
                *reinterpret_cast<const u16x8*>(&alds[arow * 128 + ((kk * 32 + lg * 8) ^ aswz)]));
#pragma unroll
        for (int n = 0; n < 2; ++n) {
            f32x4 a4 = {0.f, 0.f, 0.f, 0.f};
#pragma unroll
            for (int kk = 0; kk < 4; ++kk)
                a4 = __builtin_amdgcn_mfma_f32_16x16x32_bf16(af[kk], bf[n][kk], a4, 0, 0, 0);
            const int j = w * 32 + n * 16 + lr;
#pragma unroll
            for (int r = 0; r < 4; ++r) {
                int rr = r0 + m * 16 + lg * 4 + r;
                if (rr < Nn) {
                    float z = a4[r] + bv[n];
                    Y[(long)rr * H + j] = z;
                    ps[n] += z;
                    ps2[n] += z * z;
                }
            }
        }
    }
#pragma unroll
    for (int n = 0; n < 2; ++n) {
        float s = ps[n];
        s += __shfl_xor(s, 16);
        s += __shfl_xor(s, 32);
        float s2 = ps2[n];
        s2 += __shfl_xor(s2, 16);
        s2 += __shfl_xor(s2, 32);
        if (lg == 0) {
            int j = w * 32 + n * 16 + lr;
            atomicAdd(&csum[j], s);
            atomicAdd(&cssq[j], s2);
        }
    }
}

__global__ void finalize_bn(const float* __restrict__ csum, const float* __restrict__ cssq,
                            const float* __restrict__ g, const float* __restrict__ be,
                            float* __restrict__ scl, float* __restrict__ shf, float invN)
{
    int j = threadIdx.x;
    float mu = csum[j] * invN;
    float var = fmaxf(cssq[j] * invN - mu * mu, 0.f);
    float s = g[j] * rsqrtf(var + EPS);
    scl[j] = s;
    shf[j] = be[j] - mu * s;
}

__global__ __launch_bounds__(256) void final_gelu(
    const float* __restrict__ Y2, const float* __restrict__ scl,
    const float* __restrict__ shf, float* __restrict__ out, long n4)
{
    long i = (long)blockIdx.x * blockDim.x + threadIdx.x;
    const long stride = (long)gridDim.x * blockDim.x;
    for (; i < n4; i += stride) {
        f32x4 v = reinterpret_cast<const f32x4*>(Y2)[i];
        int c4 = (int)(i & 31);
        f32x4 sc = reinterpret_cast<const f32x4*>(scl)[c4];
        f32x4 sh = reinterpret_cast<const f32x4*>(shf)[c4];
        f32x4 o;
#pragma unroll
        for (int c = 0; c < 4; ++c) o[c] = gelu_fast(v[c] * sc[c] + sh[c]);
        reinterpret_cast<f32x4*>(out)[i] = o;
    }
}

extern "C" void kernel_launch(void* const* d_in, const int* in_sizes, int n_in,
                              void* d_out, int out_size, void* d_ws, size_t ws_size,
                              hipStream_t stream) {
    const float* x     = (const float*)d_in[0];
    const float* ea    = (const float*)d_in[1];
    const float* bases = (const float*)d_in[2];
    const int*   src   = (const int*)d_in[3];
    const int*   dst   = (const int*)d_in[4];
    const float* W1    = (const float*)d_in[5];
    const float* b1    = (const float*)d_in[6];
    const float* W2    = (const float*)d_in[7];
    const float* b2    = (const float*)d_in[8];
    const float* g1    = (const float*)d_in[9];
    const float* be1   = (const float*)d_in[10];
    const float* W3    = (const float*)d_in[11];
    const float* b3    = (const float*)d_in[12];
    const float* g2    = (const float*)d_in[13];
    const float* be2   = (const float*)d_in[14];

    const int N = in_sizes[0] / H;
    const int E = in_sizes[1] / H;

    float* ws    = (float*)d_ws;
    float* aggr  = ws;                        // [N,H]; reused as y2
    float* y1    = aggr + (size_t)N * H;      // [N,H]
    float* stats = y1 + (size_t)N * H;        // 1024 floats
    float* sum1 = stats,        *ss1 = stats + 128;
    float* sum2 = stats + 256,  *ss2 = stats + 384;
    float* scl1 = stats + 512,  *shf1 = stats + 640;
    float* scl2 = stats + 768,  *shf2 = stats + 896;
    int* cnt  = (int*)(stats + 1024);         // [N] histogram
    int* cnt2 = cnt + N;                      // [N] scatter cursor (zeroed)
    int* perm = cnt2 + N;                     // [E]
    int* dsts = perm + E;                     // [E] node id per sorted pos
    int* offs = dsts + E;                     // [N+1]

    // zero stats + cnt + cnt2, and aggr (atomic accumulation target)
    const int zn4 = (1024 + 2 * N + 3) / 4;
    zero_kernel<<<128, 256, 0, stream>>>((int*)stats, zn4);
    zero_kernel<<<1024, 256, 0, stream>>>((int*)aggr, N * H / 4);

    // --- counting sort (perm + dsts + offs) ---
    hist_kernel<<<2048, 256, 0, stream>>>(dst, cnt, E);
    scan_kernel<<<1, 1024, 0, stream>>>(cnt, offs, N, E);
    scatter_perm<<<2048, 256, 0, stream>>>(dst, offs, cnt2, perm, dsts, E);

    // --- fully-fused edge phase with async global_load_lds staging ---
    edge_aggr<<<(E + 63) / 64, 256, 0, stream>>>(x, ea, bases, src, perm, dsts,
                                                 W1, b1, aggr, E);

    // --- node pipeline ---
    const int nblk = (N + 63) / 64;
    node_gemm<false><<<nblk, 256, 0, stream>>>(aggr, W2, b2, nullptr, nullptr, y1, sum1, ss1, N);
    finalize_bn<<<1, 128, 0, stream>>>(sum1, ss1, g1, be1, scl1, shf1, 1.0f / (float)N);
    node_gemm<true><<<nblk, 256, 0, stream>>>(y1, W3, b3, scl1, shf1, aggr, sum2, ss2, N);
    finalize_bn<<<1, 128, 0, stream>>>(sum2, ss2, g2, be2, scl2, shf2, 1.0f / (float)N);

    long n4 = (long)N * H / 4;
    final_gelu<<<2048, 256, 0, stream>>>(aggr, scl2, shf2, (float*)d_out, n4);
}

// Round 13
// 393.573 us; speedup vs baseline: 1.4617x; 1.1771x over previous
//
#include <hip/hip_runtime.h>
#include <cmath>

#define H 128
#define EPS 1e-5f

typedef __attribute__((ext_vector_type(8))) __bf16 bf16x8;
typedef __attribute__((ext_vector_type(4))) float f32x4;
typedef __attribute__((ext_vector_type(2))) float f32x2;
typedef __attribute__((ext_vector_type(4))) unsigned short u16x4;
typedef __attribute__((ext_vector_type(8))) unsigned short u16x8;
typedef __attribute__((ext_vector_type(4))) int i32x4;

// Fast GELU (sigmoid form); verified R9: absmax unchanged vs erff.
__device__ __forceinline__ float gelu_fast(float x) {
    float t2 = -1.5957691216057308f * fmaf(0.044715f * x * x, x, x); // -2t
    return x * __builtin_amdgcn_rcpf(1.0f + __expf(t2));
}

__device__ __forceinline__ unsigned short f2bfu(float f) {
    __bf16 h = (__bf16)f;   // RNE fptrunc
    return __builtin_bit_cast(unsigned short, h);
}

__device__ __forceinline__ float bfu2f(unsigned short u) {
    return __builtin_bit_cast(float, (unsigned)u << 16);
}

// async global -> LDS, 16B per lane (lane i lands at ldsbase + i*16).
__device__ __forceinline__ void gld16(const void* g, void* l) {
    __builtin_amdgcn_global_load_lds(
        (__attribute__((address_space(1))) void*)(g),
        (__attribute__((address_space(3))) void*)(l), 16, 0, 0);
}

// ---------------------------------------------------------------------------
// Zero scratch (in-graph hipMemsetAsync measured 195us for 324 KB in R7).
// ---------------------------------------------------------------------------
__global__ __launch_bounds__(256) void zero_kernel(int* __restrict__ p, int n4)
{
    int i = blockIdx.x * blockDim.x + threadIdx.x;
    const int stride = gridDim.x * blockDim.x;
    i32x4 z = {0, 0, 0, 0};
    for (; i < n4; i += stride)
        reinterpret_cast<i32x4*>(p)[i] = z;
}

// ---------------------------------------------------------------------------
// x -> bf16 (halves the edge kernel's x gather traffic; enables async x).
// ---------------------------------------------------------------------------
__global__ __launch_bounds__(256) void convert_x(const float* __restrict__ x,
                                                 unsigned short* __restrict__ xb,
                                                 long n8)
{
    long i = (long)blockIdx.x * blockDim.x + threadIdx.x;
    const long stride = (long)gridDim.x * blockDim.x;
    for (; i < n8; i += stride) {
        f32x4 a = *reinterpret_cast<const f32x4*>(x + i * 8);
        f32x4 b = *reinterpret_cast<const f32x4*>(x + i * 8 + 4);
        u16x8 o;
#pragma unroll
        for (int j = 0; j < 4; ++j) { o[j] = f2bfu(a[j]); o[j + 4] = f2bfu(b[j]); }
        *reinterpret_cast<u16x8*>(xb + i * 8) = o;
    }
}

// ---------------------------------------------------------------------------
// Counting sort of edges by dst -> perm, dsts, offs. Multi-block scan.
// ---------------------------------------------------------------------------
__global__ __launch_bounds__(256) void hist_kernel(const int* __restrict__ dst,
                                                   int* __restrict__ cnt, int E)
{
    int i = blockIdx.x * blockDim.x + threadIdx.x;
    const int stride = gridDim.x * blockDim.x;
    for (; i < E; i += stride) atomicAdd(&cnt[dst[i]], 1);
}

__global__ __launch_bounds__(256) void scan_p1(const int* __restrict__ cnt,
                                               int* __restrict__ otmp,
                                               int* __restrict__ bsum, int Nn)
{
    __shared__ int sh[256];
    const int t = threadIdx.x;
    const int idx = blockIdx.x * 256 + t;
    int v = idx < Nn ? cnt[idx] : 0;
    sh[t] = v;
    __syncthreads();
    for (int d = 1; d < 256; d <<= 1) {
        int u = (t >= d) ? sh[t - d] : 0;
        __syncthreads();
        sh[t] += u;
        __syncthreads();
    }
    if (idx < Nn) otmp[idx] = sh[t] - v;      // exclusive within block
    if (t == 255) bsum[blockIdx.x] = sh[t];   // block total
}

__global__ __launch_bounds__(256) void scan_p2(const int* __restrict__ bsum,
                                               int* __restrict__ boff, int nb,
                                               int* __restrict__ offs, int Nn, int E)
{
    __shared__ int sh[256];
    const int t = threadIdx.x;
    int v = t < nb ? bsum[t] : 0;
    sh[t] = v;
    __syncthreads();
    for (int d = 1; d < 256; d <<= 1) {
        int u = (t >= d) ? sh[t - d] : 0;
        __syncthreads();
        sh[t] += u;
        __syncthreads();
    }
    if (t < nb) boff[t] = sh[t] - v;          // exclusive block offsets
    if (t == 0) offs[Nn] = E;
}

__global__ __launch_bounds__(256) void scan_p3(const int* __restrict__ otmp,
                                               const int* __restrict__ boff,
                                               int* __restrict__ offs, int Nn)
{
    const int idx = blockIdx.x * 256 + threadIdx.x;
    if (idx < Nn) offs[idx] = otmp[idx] + boff[blockIdx.x];
}

__global__ __launch_bounds__(256) void scatter_perm(const int* __restrict__ dst,
                                                    const int* __restrict__ offs,
                                                    int* __restrict__ cur2,
                                                    int* __restrict__ perm,
                                                    int* __restrict__ dsts, int E)
{
    int i = blockIdx.x * blockDim.x + threadIdx.x;
    const int stride = gridDim.x * blockDim.x;
    for (; i < E; i += stride) {
        int n = dst[i];
        int p = offs[n] + atomicAdd(&cur2[n], 1);
        perm[p] = i;
        dsts[p] = n;
    }
}

// ---------------------------------------------------------------------------
// FULLY-FUSED edge phase over dst-sorted edges. ALL staging async
// (global_load_lds): ea f32, bases f32, x bf16 — zero staging VALU.
// Swizzle via pre-XOR'd per-lane SOURCE chunk + XOR'd LDS read (rule #21).
// Swapped-operand MFMA (bias as C-init) -> gelu*bases -> Kogge-Stone
// segmented reduce across the 16-lane edge dim -> head-lane atomics.
// ---------------------------------------------------------------------------
__global__ __launch_bounds__(256, 2) void edge_aggr(
    const unsigned short* __restrict__ xbf, const float* __restrict__ ea,
    const float* __restrict__ bases, const int* __restrict__ src,
    const int* __restrict__ perm, const int* __restrict__ dsts,
    const float* __restrict__ W1, const float* __restrict__ b1,
    float* __restrict__ aggr, int E)
{
    __shared__ __align__(16) float ealds[64 * 128];            // 32 KB f32
    __shared__ __align__(16) float blds[64 * 128];             // 32 KB f32
    __shared__ __align__(16) unsigned short xlds[64 * 128];    // 16 KB bf16

    const int tid = threadIdx.x;
    const int w = tid >> 6, l = tid & 63, lg = l >> 4, lr = l & 15;

    // W1 A-fragments: rows w*32 + ni*16 + lr, k = kk*32 + lg*8 .. +8
    bf16x8 wf[2][4];
    f32x4 b1v[2];
#pragma unroll
    for (int ni = 0; ni < 2; ++ni) {
        int row = w * 32 + ni * 16 + lr;
#pragma unroll
        for (int kk = 0; kk < 4; ++kk) {
            const float* p = W1 + row * H + kk * 32 + lg * 8;
            u16x8 tt;
#pragma unroll
            for (int i = 0; i < 8; ++i) tt[i] = f2bfu(p[i]);
            wf[ni][kk] = __builtin_bit_cast(bf16x8, tt);
        }
        b1v[ni] = *reinterpret_cast<const f32x4*>(b1 + w * 32 + ni * 16 + lg * 4);
    }

    const int e0 = blockIdx.x * 64;
    // per-lane tile metadata: lane l <-> sorted position e0+l
    int ic = e0 + l;
    ic = ic < E ? ic : E - 1;
    const int el_reg = perm[ic];
    const int nd_reg = dsts[ic];
    const int sr_reg = src[el_reg];

    // ---- async ea + bases staging (f32, source-swizzled) ----
#pragma unroll
    for (int j = 0; j < 8; ++j) {
        const int r = (w << 4) + (j << 1) + (l >> 5);   // row 0..63 (2/instr)
        const int e = __shfl(el_reg, r);
        const int cs = (l & 31) ^ (r & 7);              // 16B-chunk of 32, pre-swz
        const int rowbase = (((w << 4) + (j << 1)) << 7);  // floats
        gld16(ea + (long)e * H + cs * 4, &ealds[rowbase]);
        gld16(bases + (long)e * H + cs * 4, &blds[rowbase]);
    }

    // ---- async x staging (bf16, source-swizzled): 4 rows/instr ----
#pragma unroll
    for (int j = 0; j < 4; ++j) {
        const int r = (w << 4) + (j << 2) + (l >> 4);   // row 0..63 (4/instr)
        const int s = __shfl(sr_reg, r);
        const int cs = (l & 15) ^ (r & 7);              // 16B-chunk of 16, pre-swz
        const int rowbase = (((w << 4) + (j << 2)) << 7);  // ushorts
        gld16(xbf + (long)s * H + cs * 8, &xlds[rowbase]);
    }
    __syncthreads();   // drains vmcnt (global_load_lds) for the whole block

    // ---- compute + in-register segmented reduction + atomic epilogue ----
    const int col0base = w * 32 + lg * 4;
#pragma unroll
    for (int s = 0; s < 4; ++s) {
        const int arow = s * 16 + lr;
        const int fswz = arow & 7;            // 16B-chunk XOR

        // posE fragments: ea (f32 LDS) + x (bf16 LDS) -> bf16 pack
        bf16x8 af[4];
#pragma unroll
        for (int kk = 0; kk < 4; ++kk) {
            const int cc = kk * 8 + lg * 2;
            f32x4 elo = *reinterpret_cast<const f32x4*>(&ealds[arow * 128 + ((cc ^ fswz) << 2)]);
            f32x4 ehi = *reinterpret_cast<const f32x4*>(&ealds[arow * 128 + (((cc + 1) ^ fswz) << 2)]);
            u16x8 xv = *reinterpret_cast<const u16x8*>(&xlds[arow * 128 + (((kk * 4 + lg) ^ fswz) << 3)]);
            u16x8 o;
#pragma unroll
            for (int r = 0; r < 4; ++r) {
                o[r]     = f2bfu(elo[r] + bfu2f(xv[r]));
                o[r + 4] = f2bfu(ehi[r] + bfu2f(xv[r + 4]));
            }
            af[kk] = __builtin_bit_cast(bf16x8, o);
        }

        const int es = e0 + arow;
        const bool ok = es < E;
        const int nd = __shfl(nd_reg, arow);
        const int ndp = __shfl(nd_reg, arow - 1);   // arow==0 masked by lr==0
        const bool head = ok && (lr == 0 || nd != ndp);

#pragma unroll
        for (int ni = 0; ni < 2; ++ni) {
            f32x4 a4 = b1v[ni];   // bias as C-init
#pragma unroll
            for (int kk = 0; kk < 4; ++kk)
                a4 = __builtin_amdgcn_mfma_f32_16x16x32_bf16(wf[ni][kk], af[kk], a4, 0, 0, 0);

            const int col0 = col0base + ni * 16;
            const int bcc = col0 >> 2;
            f32x4 bq = *reinterpret_cast<const f32x4*>(&blds[arow * 128 + ((bcc ^ fswz) << 2)]);
            f32x4 v;
#pragma unroll
            for (int r = 0; r < 4; ++r)
                v[r] = ok ? gelu_fast(a4[r]) * bq[r] : 0.f;

            // Kogge-Stone segmented suffix-sum across lr (16-lane groups)
#pragma unroll
            for (int d = 1; d < 16; d <<= 1) {
                f32x4 vn;
#pragma unroll
                for (int r = 0; r < 4; ++r) vn[r] = __shfl_down(v[r], d);
                int ndn = __shfl_down(nd, d);
                bool take = (lr + d < 16) && (ndn == nd);
#pragma unroll
                for (int r = 0; r < 4; ++r) v[r] += take ? vn[r] : 0.f;
            }

            if (head) {
                float* dstp = aggr + (long)nd * H + col0;
#pragma unroll
                for (int r = 0; r < 4; ++r) atomicAdd(&dstp[r], v[r]);
            }
        }
    }
}

// ---------------------------------------------------------------------------
// Node GEMM  Y = f(A) @ W^T + bias, fused column sum/sumsq epilogue for BN
// stats. PRE=true applies gelu(a*scale+shift) on load.
// ---------------------------------------------------------------------------
template <bool PRE>
__global__ __launch_bounds__(256) void node_gemm(
    const float* __restrict__ A, const float* __restrict__ W,
    const float* __restrict__ bias, const float* __restrict__ scl,
    const float* __restrict__ shf, float* __restrict__ Y,
    float* __restrict__ csum, float* __restrict__ cssq, int Nn)
{
    __shared__ __align__(16) unsigned short alds[64 * 128];

    const int tid = threadIdx.x;
    const int w = tid >> 6, l = tid & 63, lg = l >> 4, lr = l & 15;
    const int er = tid >> 2, q = tid & 3;
    const int r0 = blockIdx.x * 64;

    bf16x8 bf[2][4];
    float bv[2];
#pragma unroll
    for (int n = 0; n < 2; ++n) {
        int row = w * 32 + n * 16 + lr;
        bv[n] = bias[row];
#pragma unroll
        for (int kk = 0; kk < 4; ++kk) {
            const float* p = W + row * H + kk * 32 + lg * 8;
            u16x8 t;
#pragma unroll
            for (int i = 0; i < 8; ++i) t[i] = f2bfu(p[i]);
            bf[n][kk] = __builtin_bit_cast(bf16x8, t);
        }
    }

    {
        int rr = r0 + er;
        int rc = rr < Nn ? rr : Nn - 1;
        const f32x4* pa = reinterpret_cast<const f32x4*>(A + (long)rc * H + q * 32);
        const int swz = (er & 7) << 3;
#pragma unroll
        for (int i = 0; i < 8; ++i) {
            f32x4 v = pa[i];
            if constexpr (PRE) {
                f32x4 sc = *reinterpret_cast<const f32x4*>(scl + q * 32 + i * 4);
                f32x4 sh = *reinterpret_cast<const f32x4*>(shf + q * 32 + i * 4);
#pragma unroll
                for (int c = 0; c < 4; ++c) v[c] = gelu_fast(v[c] * sc[c] + sh[c]);
            }
            u16x4 o;
            o[0] = f2bfu(v[0]);
            o[1] = f2bfu(v[1]);
            o[2] = f2bfu(v[2]);
            o[3] = f2bfu(v[3]);
            int col = q * 32 + i * 4;
            *reinterpret_cast<u16x4*>(&alds[er * 128 + (col ^ swz)]) = o;
        }
    }
    __syncthreads();

    float ps[2] = {0.f, 0.f}, ps2[2] = {0.f, 0.f};
#pragma unroll
    for (int m = 0; m < 4; ++m) {
        const int arow = m * 16 + lr;
        const int aswz = (arow & 7) << 3;
        bf16x8 af[4];
#pragma unroll
        for (int kk = 0; kk < 4; ++kk)
            af[kk] = __builtin_bit_cast(bf16x8,
                *reinterpret_cast<const u16x8*>(&alds[arow * 128 + ((kk * 32 + lg * 8) ^ aswz)]));
#pragma unroll
        for (int n = 0; n < 2; ++n) {
            f32x4 a4 = {0.f, 0.f, 0.f, 0.f};
#pragma unroll
            for (int kk = 0; kk < 4; ++kk)
                a4 = __builtin_amdgcn_mfma_f32_16x16x32_bf16(af[kk], bf[n][kk], a4, 0, 0, 0);
            const int j = w * 32 + n * 16 + lr;
#pragma unroll
            for (int r = 0; r < 4; ++r) {
                int rr = r0 + m * 16 + lg * 4 + r;
                if (rr < Nn) {
                    float z = a4[r] + bv[n];
                    Y[(long)rr * H + j] = z;
                    ps[n] += z;
                    ps2[n] += z * z;
                }
            }
        }
    }
#pragma unroll
    for (int n = 0; n < 2; ++n) {
        float s = ps[n];
        s += __shfl_xor(s, 16);
        s += __shfl_xor(s, 32);
        float s2 = ps2[n];
        s2 += __shfl_xor(s2, 16);
        s2 += __shfl_xor(s2, 32);
        if (lg == 0) {
            int j = w * 32 + n * 16 + lr;
            atomicAdd(&csum[j], s);
            atomicAdd(&cssq[j], s2);
        }
    }
}

__global__ void finalize_bn(const float* __restrict__ csum, const float* __restrict__ cssq,
                            const float* __restrict__ g, const float* __restrict__ be,
                            float* __restrict__ scl, float* __restrict__ shf, float invN)
{
    int j = threadIdx.x;
    float mu = csum[j] * invN;
    float var = fmaxf(cssq[j] * invN - mu * mu, 0.f);
    float s = g[j] * rsqrtf(var + EPS);
    scl[j] = s;
    shf[j] = be[j] - mu * s;
}

__global__ __launch_bounds__(256) void final_gelu(
    const float* __restrict__ Y2, const float* __restrict__ scl,
    const float* __restrict__ shf, float* __restrict__ out, long n4)
{
    long i = (long)blockIdx.x * blockDim.x + threadIdx.x;
    const long stride = (long)gridDim.x * blockDim.x;
    for (; i < n4; i += stride) {
        f32x4 v = reinterpret_cast<const f32x4*>(Y2)[i];
        int c4 = (int)(i & 31);
        f32x4 sc = reinterpret_cast<const f32x4*>(scl)[c4];
        f32x4 sh = reinterpret_cast<const f32x4*>(shf)[c4];
        f32x4 o;
#pragma unroll
        for (int c = 0; c < 4; ++c) o[c] = gelu_fast(v[c] * sc[c] + sh[c]);
        reinterpret_cast<f32x4*>(out)[i] = o;
    }
}

extern "C" void kernel_launch(void* const* d_in, const int* in_sizes, int n_in,
                              void* d_out, int out_size, void* d_ws, size_t ws_size,
                              hipStream_t stream) {
    const float* x     = (const float*)d_in[0];
    const float* ea    = (const float*)d_in[1];
    const float* bases = (const float*)d_in[2];
    const int*   src   = (const int*)d_in[3];
    const int*   dst   = (const int*)d_in[4];
    const float* W1    = (const float*)d_in[5];
    const float* b1    = (const float*)d_in[6];
    const float* W2    = (const float*)d_in[7];
    const float* b2    = (const float*)d_in[8];
    const float* g1    = (const float*)d_in[9];
    const float* be1   = (const float*)d_in[10];
    const float* W3    = (const float*)d_in[11];
    const float* b3    = (const float*)d_in[12];
    const float* g2    = (const float*)d_in[13];
    const float* be2   = (const float*)d_in[14];

    const int N = in_sizes[0] / H;
    const int E = in_sizes[1] / H;

    float* ws    = (float*)d_ws;
    float* aggr  = ws;                        // [N,H]; reused as y2
    float* y1    = aggr + (size_t)N * H;      // [N,H]
    float* stats = y1 + (size_t)N * H;        // 1024 floats
    float* sum1 = stats,        *ss1 = stats + 128;
    float* sum2 = stats + 256,  *ss2 = stats + 384;
    float* scl1 = stats + 512,  *shf1 = stats + 640;
    float* scl2 = stats + 768,  *shf2 = stats + 896;
    int* cnt  = (int*)(stats + 1024);         // [N] histogram
    int* cnt2 = cnt + N;                      // [N] scatter cursor (zeroed)
    int* perm = cnt2 + N;                     // [E]
    int* dsts = perm + E;                     // [E]
    int* offs = dsts + E;                     // [N+1]
    int* otmp = offs + N + 1;                 // [N] scan scratch
    int* bsum = otmp + N;                     // [256]
    int* boff = bsum + 256;                   // [256]
    unsigned short* xbf = (unsigned short*)(((uintptr_t)(boff + 256) + 4095) & ~(uintptr_t)4095); // [N,H] bf16

    // zero stats + cnt + cnt2, and aggr (atomic accumulation target)
    const int zn4 = (1024 + 2 * N + 3) / 4;
    zero_kernel<<<128, 256, 0, stream>>>((int*)stats, zn4);
    zero_kernel<<<1024, 256, 0, stream>>>((int*)aggr, N * H / 4);

    // x -> bf16
    convert_x<<<2048, 256, 0, stream>>>(x, xbf, (long)N * H / 8);

    // --- counting sort (perm + dsts + offs), multi-block scan ---
    const int nsb = (N + 255) / 256;
    hist_kernel<<<2048, 256, 0, stream>>>(dst, cnt, E);
    scan_p1<<<nsb, 256, 0, stream>>>(cnt, otmp, bsum, N);
    scan_p2<<<1, 256, 0, stream>>>(bsum, boff, nsb, offs, N, E);
    scan_p3<<<nsb, 256, 0, stream>>>(otmp, boff, offs, N);
    scatter_perm<<<2048, 256, 0, stream>>>(dst, offs, cnt2, perm, dsts, E);

    // --- fully-fused edge phase, all-async staging ---
    edge_aggr<<<(E + 63) / 64, 256, 0, stream>>>(xbf, ea, bases, src, perm, dsts,
                                                 W1, b1, aggr, E);

    // --- node pipeline ---
    const int nblk = (N + 63) / 64;
    node_gemm<false><<<nblk, 256, 0, stream>>>(aggr, W2, b2, nullptr, nullptr, y1, sum1, ss1, N);
    finalize_bn<<<1, 128, 0, stream>>>(sum1, ss1, g1, be1, scl1, shf1, 1.0f / (float)N);
    node_gemm<true><<<nblk, 256, 0, stream>>>(y1, W3, b3, scl1, shf1, aggr, sum2, ss2, N);
    finalize_bn<<<1, 128, 0, stream>>>(sum2, ss2, g2, be2, scl2, shf2, 1.0f / (float)N);

    long n4 = (long)N * H / 4;
    final_gelu<<<2048, 256, 0, stream>>>(aggr, scl2, shf2, (float*)d_out, n4);
}